// Round 9
// baseline (407.457 us; speedup 1.0000x reference)
//
#include <hip/hip_runtime.h>
#include <stdint.h>

#define DEV __device__ __forceinline__

typedef unsigned short u16;
typedef __bf16 bf16x8 __attribute__((ext_vector_type(8)));
typedef float f32x4 __attribute__((ext_vector_type(4)));
typedef u16 u16x8 __attribute__((ext_vector_type(8)));

#define MFMA_BF16(A, B, C) __builtin_amdgcn_mfma_f32_16x16x32_bf16(A, B, C, 0, 0, 0)
#define EXP2(x) __builtin_amdgcn_exp2f(x)

DEV u16 f2bf(float f) {
    unsigned x;
    __builtin_memcpy(&x, &f, 4);
    unsigned r = (x + 0x7fffu + ((x >> 16) & 1u)) >> 16;  // RNE
    return (u16)r;
}

DEV u16 f2bf_fast(float f) {  // round-half-up; 2 VALU ops, used in attn hot loop
    unsigned x;
    __builtin_memcpy(&x, &f, 4);
    return (u16)((x + 0x8000u) >> 16);
}

DEV void storeC(u16* p, float v) { *p = f2bf(v); }
DEV void storeC(float* p, float v) { *p = v; }

// async global->LDS, 16B per lane. LDS dest must be wave-uniform base + lane*16.
DEV void async_copy16(const u16* g, u16* l) {
    __builtin_amdgcn_global_load_lds(
        (__attribute__((address_space(1))) unsigned int*)g,
        (__attribute__((address_space(3))) unsigned int*)l, 16, 0, 0);
}

// ---------------------------------------------------------------------------
// fused fp32 -> bf16 conversion of x | wqkv | wout into one contiguous dest.
// ---------------------------------------------------------------------------
constexpr int N_X = 8192 * 1024, N_WQ = 3072 * 1024, N_WO = 1024 * 1024;

__global__ __launch_bounds__(256)
void cvt_all(const float* __restrict__ x, const float* __restrict__ wq,
             const float* __restrict__ wo, u16* __restrict__ out) {
    const int i = (blockIdx.x * 256 + threadIdx.x) * 4;
    const float* src;
    if (i < N_X) src = x + i;
    else if (i < N_X + N_WQ) src = wq + (i - N_X);
    else src = wo + (i - N_X - N_WQ);
    const float4 v = *(const float4*)src;
    ushort4 o;
    o.x = f2bf(v.x);
    o.y = f2bf(v.y);
    o.z = f2bf(v.z);
    o.w = f2bf(v.w);
    *(ushort4*)(out + i) = o;
}

// ---------------------------------------------------------------------------
// C[M,N] = A[M,K] * Bw[N,K]^T + bias[N]; A,Bw bf16, bias fp32, fp32 accum.
// 128x128 tile, BK=64 as two 32-wide panels. Grid: x = M-block (XCD-local A).
// launch_bounds (256,3): cap VGPR ~170 -> 3 blocks/CU to hide barrier drain.
// VSPLIT: cols >= 2048 (V third of QKV) stored TRANSPOSED into vT[col-2048][M].
// ---------------------------------------------------------------------------
template <typename OT, bool VSPLIT>
__global__ __launch_bounds__(256, 3)
void gemm_bt_bias(const u16* __restrict__ A, const u16* __restrict__ Bw,
                  const float* __restrict__ bias, OT* __restrict__ C,
                  u16* __restrict__ vT, int M, int N, int K) {
    __shared__ __attribute__((aligned(16))) u16 sA[2][128 * 32];
    __shared__ __attribute__((aligned(16))) u16 sB[2][128 * 32];

    const int tid  = threadIdx.x;
    const int lane = tid & 63;
    const int wave = tid >> 6;
    const int m0 = blockIdx.x * 128;   // M on x: XCD-local A reuse
    const int n0 = blockIdx.y * 128;
    const int wm = (wave & 1) * 64;
    const int wn = (wave >> 1) * 64;
    const int fr = lane & 15;
    const int q4 = lane >> 4;

    const int r0 = tid >> 2;
    const int c0 = (tid & 3) * 8;
    const u16* gA0 = A + (size_t)(m0 + r0) * K + c0;
    const u16* gA1 = A + (size_t)(m0 + 64 + r0) * K + c0;
    const u16* gB0 = Bw + (size_t)(n0 + r0) * K + c0;
    const u16* gB1 = Bw + (size_t)(n0 + 64 + r0) * K + c0;

    f32x4 acc[4][4];
#pragma unroll
    for (int i = 0; i < 4; i++)
#pragma unroll
        for (int j = 0; j < 4; j++) acc[i][j] = (f32x4){0.f, 0.f, 0.f, 0.f};

    for (int k0 = 0; k0 < K; k0 += 64) {
#pragma unroll
        for (int p = 0; p < 2; ++p) {  // two 32-wide K panels
            async_copy16(gA0 + k0 + p * 32, &sA[p][tid * 8]);
            async_copy16(gA1 + k0 + p * 32, &sA[p][2048 + tid * 8]);
            async_copy16(gB0 + k0 + p * 32, &sB[p][tid * 8]);
            async_copy16(gB1 + k0 + p * 32, &sB[p][2048 + tid * 8]);
        }
        __syncthreads();

#pragma unroll
        for (int p = 0; p < 2; ++p) {
            bf16x8 af[4], bfr[4];
#pragma unroll
            for (int i = 0; i < 4; i++)
                af[i] = *(const bf16x8*)&sA[p][(wm + i * 16 + fr) * 32 + q4 * 8];
#pragma unroll
            for (int j = 0; j < 4; j++)
                bfr[j] = *(const bf16x8*)&sB[p][(wn + j * 16 + fr) * 32 + q4 * 8];
#pragma unroll
            for (int i = 0; i < 4; i++)
#pragma unroll
                for (int j = 0; j < 4; j++)
                    acc[i][j] = MFMA_BF16(af[i], bfr[j], acc[i][j]);
        }
        __syncthreads();
    }

    // epilogue: C/D layout col=lane&15, row=quad*4+reg  [verified m89/m91]
#pragma unroll
    for (int j = 0; j < 4; j++) {
        const int col = n0 + wn + j * 16 + fr;
        const float bv = bias[col];
        if (VSPLIT && col >= 2048) {  // wave-uniform: col/16 uniform across fr
#pragma unroll
            for (int i = 0; i < 4; i++) {
                const int row = m0 + wm + i * 16 + q4 * 4;
                ushort4 o;
                o.x = f2bf(acc[i][j][0] + bv);
                o.y = f2bf(acc[i][j][1] + bv);
                o.z = f2bf(acc[i][j][2] + bv);
                o.w = f2bf(acc[i][j][3] + bv);
                *(ushort4*)&vT[(size_t)(col - 2048) * 8192 + row] = o;
            }
        } else {
#pragma unroll
            for (int i = 0; i < 4; i++) {
                const int row = m0 + wm + i * 16 + q4 * 4;
#pragma unroll
                for (int r = 0; r < 4; r++)
                    storeC(&C[(size_t)(row + r) * N + col], acc[i][j][r] + bv);
            }
        }
    }
}

// ---------------------------------------------------------------------------
// Flash attention, causal, S^T/O^T, PAIRED Q-TILES, XCD-GROUPED, BARRIER-FREE.
// K and V fragments are loaded DIRECTLY from global (L2-hot after XCD
// grouping: K 256KB + V 512KB per (b,h), 8 groups/XCD ~ L2 capacity); both
// layouts read 16 rows x 64B contiguous per wave-load. LDS holds only the
// per-wave P buffer -> no __syncthreads in the loop; waves run independently.
//   S^T = K Q^T : C-layout row = key (q4*4+r), col = q (fr); softmax state is
//   per-lane scalar; P packed ushort4; O^T = V^T P^T.
// ---------------------------------------------------------------------------
constexpr int Lc = 2048, Dc = 1024;

__global__ __launch_bounds__(256, 4)
void attn_fa(const u16* __restrict__ qkv, const u16* __restrict__ vT,
             u16* __restrict__ outb) {
    __shared__ __attribute__((aligned(16))) u16 sP[4][2][16 * 72];  // [wave][tile][q][key]

    const int tid  = threadIdx.x;
    const int lane = tid & 63;
    const int wave = tid >> 6;
    const int fr = lane & 15;
    const int q4 = lane >> 4;

    const int id = blockIdx.x;                  // 0..1023
    const int g  = (id & 7) + 8 * (id >> 7);    // (b,h) group, XCD = g & 7
    const int bx = (id >> 3) & 15;              // 0..15
    const int h = g & 15;
    const int b = g >> 4;
    const int qblkA = bx;                       // short tile
    const int qblkB = 31 - bx;                  // long tile

    constexpr float CEXP = 0.18033688011112042f;  // 0.125 * log2(e)

    // Q fragments (B-operand: n=fr -> q row, k=q4*8+j -> d)
    const int qrowA = qblkA * 64 + wave * 16 + fr;
    const int qrowB = qblkB * 64 + wave * 16 + fr;
    const u16* qptrA = qkv + ((size_t)(b * Lc + qrowA) * 3) * Dc + h * 64;
    const u16* qptrB = qkv + ((size_t)(b * Lc + qrowB) * 3) * Dc + h * 64;
    bf16x8 qfA[2], qfB[2];
    qfA[0] = *(const bf16x8*)(qptrA + q4 * 8);
    qfA[1] = *(const bf16x8*)(qptrA + 32 + q4 * 8);
    qfB[0] = *(const bf16x8*)(qptrB + q4 * 8);
    qfB[1] = *(const bf16x8*)(qptrB + 32 + q4 * 8);

    f32x4 oA[4], oB[4];
#pragma unroll
    for (int t = 0; t < 4; t++) {
        oA[t] = (f32x4){0.f, 0.f, 0.f, 0.f};
        oB[t] = (f32x4){0.f, 0.f, 0.f, 0.f};
    }
    float mA = -3.4e38f, lA = 0.f, mB = -3.4e38f, lB = 0.f;

    const int q_local = wave * 16 + fr;

    // K rows: qkv[token][3][H][64], K third; lane reads row (t*16+fr), 16B chunk q4
    const u16* kbase0 = qkv + ((size_t)(b * Lc) * 3 + 1) * Dc + h * 64 + (size_t)fr * 3072 + q4 * 8;
    // V^T rows: vT[d][token]; lane reads row (t*16+fr), 16B chunk q4 within 64-key tile
    const u16* vbase0 = vT + ((size_t)(h * 64 + fr)) * 8192 + b * Lc + q4 * 8;

    u16* sPA = &sP[wave][0][0];
    u16* sPB = &sP[wave][1][0];

    for (int jb = 0; jb <= qblkB; ++jb) {
        const bool doA = (jb <= qblkA);  // wave-uniform
        const u16* kb = kbase0 + (size_t)(jb * 64) * 3072;

        // S^T = K Q^T, K fragments direct from global (L2)
        f32x4 sA_[4], sB_[4];
#pragma unroll
        for (int t = 0; t < 4; t++) {
            const bf16x8 kf0 = *(const bf16x8*)(kb + (size_t)(t * 16) * 3072);
            const bf16x8 kf1 = *(const bf16x8*)(kb + (size_t)(t * 16) * 3072 + 32);
            sB_[t] = (f32x4){0.f, 0.f, 0.f, 0.f};
            sB_[t] = MFMA_BF16(kf0, qfB[0], sB_[t]);
            sB_[t] = MFMA_BF16(kf1, qfB[1], sB_[t]);
            if (doA) {
                sA_[t] = (f32x4){0.f, 0.f, 0.f, 0.f};
                sA_[t] = MFMA_BF16(kf0, qfA[0], sA_[t]);
                sA_[t] = MFMA_BF16(kf1, qfA[1], sA_[t]);
            }
        }

        // ---- tile B softmax ----
        {
            if (jb == qblkB) {
#pragma unroll
                for (int t = 0; t < 4; t++)
#pragma unroll
                    for (int r = 0; r < 4; r++)
                        if (t * 16 + q4 * 4 + r > q_local) sB_[t][r] = -1e30f;
            }
            float mx = sB_[0][0];
#pragma unroll
            for (int t = 0; t < 4; t++)
#pragma unroll
                for (int r = 0; r < 4; r++) mx = fmaxf(mx, sB_[t][r]);
            mx = fmaxf(mx, __shfl_xor(mx, 16));
            mx = fmaxf(mx, __shfl_xor(mx, 32));
            const float mnew = fmaxf(mB, mx);
            const float alpha = EXP2((mB - mnew) * CEXP);
            float sum = 0.f;
#pragma unroll
            for (int t = 0; t < 4; t++) {
#pragma unroll
                for (int r = 0; r < 4; r++) {
                    const float p = EXP2((sB_[t][r] - mnew) * CEXP);
                    sB_[t][r] = p;
                    sum += p;
                }
                ushort4 o;
                o.x = f2bf_fast(sB_[t][0]);
                o.y = f2bf_fast(sB_[t][1]);
                o.z = f2bf_fast(sB_[t][2]);
                o.w = f2bf_fast(sB_[t][3]);
                *(ushort4*)&sPB[fr * 72 + t * 16 + q4 * 4] = o;
            }
            sum += __shfl_xor(sum, 16);
            sum += __shfl_xor(sum, 32);
            lB = alpha * lB + sum;
            mB = mnew;
#pragma unroll
            for (int t = 0; t < 4; t++)
#pragma unroll
                for (int r = 0; r < 4; r++) oB[t][r] *= alpha;
        }

        // ---- tile A softmax ----
        if (doA) {
            if (jb == qblkA) {
#pragma unroll
                for (int t = 0; t < 4; t++)
#pragma unroll
                    for (int r = 0; r < 4; r++)
                        if (t * 16 + q4 * 4 + r > q_local) sA_[t][r] = -1e30f;
            }
            float mx = sA_[0][0];
#pragma unroll
            for (int t = 0; t < 4; t++)
#pragma unroll
                for (int r = 0; r < 4; r++) mx = fmaxf(mx, sA_[t][r]);
            mx = fmaxf(mx, __shfl_xor(mx, 16));
            mx = fmaxf(mx, __shfl_xor(mx, 32));
            const float mnew = fmaxf(mA, mx);
            const float alpha = EXP2((mA - mnew) * CEXP);
            float sum = 0.f;
#pragma unroll
            for (int t = 0; t < 4; t++) {
#pragma unroll
                for (int r = 0; r < 4; r++) {
                    const float p = EXP2((sA_[t][r] - mnew) * CEXP);
                    sA_[t][r] = p;
                    sum += p;
                }
                ushort4 o;
                o.x = f2bf_fast(sA_[t][0]);
                o.y = f2bf_fast(sA_[t][1]);
                o.z = f2bf_fast(sA_[t][2]);
                o.w = f2bf_fast(sA_[t][3]);
                *(ushort4*)&sPA[fr * 72 + t * 16 + q4 * 4] = o;
            }
            sum += __shfl_xor(sum, 16);
            sum += __shfl_xor(sum, 32);
            lA = alpha * lA + sum;
            mA = mnew;
#pragma unroll
            for (int t = 0; t < 4; t++)
#pragma unroll
                for (int r = 0; r < 4; r++) oA[t][r] *= alpha;
        }

        // O^T += V^T P^T, V fragments direct from global (L2); sP wave-local
        const u16* vb = vbase0 + jb * 64;
#pragma unroll
        for (int ks = 0; ks < 2; ++ks) {
            const bf16x8 pfB = *(const bf16x8*)&sPB[fr * 72 + ks * 32 + q4 * 8];
            bf16x8 pfA;
            if (doA) pfA = *(const bf16x8*)&sPA[fr * 72 + ks * 32 + q4 * 8];
#pragma unroll
            for (int t = 0; t < 4; t++) {
                const bf16x8 vf = *(const bf16x8*)(vb + (size_t)(t * 16) * 8192 + ks * 32);
                oB[t] = MFMA_BF16(vf, pfB, oB[t]);
                if (doA) oA[t] = MFMA_BF16(vf, pfA, oA[t]);
            }
        }
    }

    // epilogue: O^T row = d = t*16+q4*4+r, col = q = fr -> packed ushort4
    const float rlA = 1.0f / lA;
    const float rlB = 1.0f / lB;
    u16* orowA = outb + (size_t)(b * Lc + qblkA * 64 + wave * 16 + fr) * Dc + h * 64;
    u16* orowB = outb + (size_t)(b * Lc + qblkB * 64 + wave * 16 + fr) * Dc + h * 64;
#pragma unroll
    for (int t = 0; t < 4; t++) {
        ushort4 a, o;
        a.x = f2bf(oA[t][0] * rlA);
        a.y = f2bf(oA[t][1] * rlA);
        a.z = f2bf(oA[t][2] * rlA);
        a.w = f2bf(oA[t][3] * rlA);
        *(ushort4*)(orowA + t * 16 + q4 * 4) = a;
        o.x = f2bf(oB[t][0] * rlB);
        o.y = f2bf(oB[t][1] * rlB);
        o.z = f2bf(oB[t][2] * rlB);
        o.w = f2bf(oB[t][3] * rlB);
        *(ushort4*)(orowB + t * 16 + q4 * 4) = o;
    }
}

// ---------------------------------------------------------------------------
extern "C" void kernel_launch(void* const* d_in, const int* in_sizes, int n_in,
                              void* d_out, int out_size, void* d_ws, size_t ws_size,
                              hipStream_t stream) {
    const float* x    = (const float*)d_in[0];  // [4,2048,1024] fp32
    const float* wqkv = (const float*)d_in[1];  // [3072,1024]
    const float* bqkv = (const float*)d_in[2];  // [3072]
    const float* wout = (const float*)d_in[3];  // [1024,1024]
    const float* bout = (const float*)d_in[4];  // [1024]
    float* out = (float*)d_out;                 // [4,2048,1024] fp32

    u16* qkv    = (u16*)d_ws;                       // [8192,3072] bf16 (V third unused)
    u16* attn   = qkv + (size_t)8192 * 3072;        // [8192,1024] bf16
    u16* xbf    = attn + (size_t)8192 * 1024;       // [8192,1024] bf16
    u16* wqkvbf = xbf + (size_t)8192 * 1024;        // [3072,1024] bf16
    u16* woutbf = wqkvbf + (size_t)3072 * 1024;     // [1024,1024] bf16
    u16* vT     = woutbf + (size_t)1024 * 1024;     // [1024, 8192] bf16 (V transposed)

    dim3 blk(256);
    cvt_all<<<(N_X + N_WQ + N_WO) / 1024, blk, 0, stream>>>(x, wqkv, wout, xbf);

    gemm_bt_bias<u16, true><<<dim3(8192 / 128, 3072 / 128), blk, 0, stream>>>(
        xbf, wqkvbf, bqkv, qkv, vT, 8192, 3072, 1024);
    attn_fa<<<dim3(1024), blk, 0, stream>>>(qkv, vT, attn);
    gemm_bt_bias<float, false><<<dim3(8192 / 128, 1024 / 128), blk, 0, stream>>>(
        attn, woutbf, bout, out, nullptr, 8192, 1024, 1024);
}